// Round 5
// baseline (337.470 us; speedup 1.0000x reference)
//
#include <hip/hip_runtime.h>
#include <hip/hip_bf16.h>

#define N_NODES 50000
#define N_EDGES 800000
#define F_IN    128
#define HC      128      // H*C

typedef __attribute__((ext_vector_type(8))) short bf16x8;
typedef __attribute__((ext_vector_type(4))) float f32x4;

__device__ __forceinline__ float bf2f(unsigned int u16) {
    return __uint_as_float(u16 << 16);
}
__device__ __forceinline__ unsigned int f2bf(float f) {
    unsigned int u = __float_as_uint(f);
    return (u + 0x7fffu + ((u >> 16) & 1u)) >> 16;   // RNE
}

// ---------------------------------------------------------------------------
// K_pc: fused. Blocks 0..3124: edge-count atomics (counts pre-zeroed by
// memset; self-loop +1 folded into the scan). Blocks 3125..3140: pack
// [Wg|Ws] into MFMA-B fragment-major bf16 (slot g=(nt*4+kq)*64+lane holds
// W[kq*32+(lane>>4)*8+j][nt*16+(lane&15)]; cols 0..127=Wg, 128..255=Ws).
// ---------------------------------------------------------------------------
__global__ __launch_bounds__(256) void k_pc(
    const int* __restrict__ dst,
    const float* __restrict__ Wg, const float* __restrict__ Ws,
    unsigned short* __restrict__ Bfrag, int* __restrict__ counts)
{
    const int bid = blockIdx.x;
    if (bid < 3125) {
        const int i = bid * 256 + threadIdx.x;
        if (i < N_EDGES) atomicAdd(&counts[dst[i]], 1);
    } else {
        const int g = (bid - 3125) * 256 + threadIdx.x;
        if (g < 4096) {
            const int lane = g & 63;
            const int kq = (g >> 6) & 3;
            const int nt = g >> 8;           // 0..15
            const int c = nt * 16 + (lane & 15);
            const int kbase = kq * 32 + (lane >> 4) * 8;
            const float* Wsel = (c < 128) ? (Wg + c) : (Ws + c - 128);
            unsigned int pk[4];
#pragma unroll
            for (int p = 0; p < 4; p++) {
                const float v0 = Wsel[(size_t)(kbase + 2 * p) * HC];
                const float v1 = Wsel[(size_t)(kbase + 2 * p + 1) * HC];
                pk[p] = f2bf(v0) | (f2bf(v1) << 16);
            }
            *(uint4*)(Bfrag + (size_t)g * 8) = make_uint4(pk[0], pk[1], pk[2], pk[3]);
        }
    }
}

// ---------------------------------------------------------------------------
// K_scan: single-block exclusive scan of (counts[i]+1) -> row_start, cursor.
// 1024 threads x 49 elements each (50176 >= 50000).
// ---------------------------------------------------------------------------
__global__ __launch_bounds__(1024) void k_scan(
    const int* __restrict__ counts,
    int* __restrict__ row_start, int* __restrict__ cursor)
{
    __shared__ int s[1024];
    const int tid = threadIdx.x;
    const int base = tid * 49;
    int t = 0;
    for (int j = 0; j < 49; j++) {
        const int idx = base + j;
        if (idx < N_NODES) t += counts[idx] + 1;
    }
    s[tid] = t;
    __syncthreads();
    for (int off = 1; off < 1024; off <<= 1) {
        const int add = (tid >= off) ? s[tid - off] : 0;
        __syncthreads();
        s[tid] += add;
        __syncthreads();
    }
    int excl = s[tid] - t;
    for (int j = 0; j < 49; j++) {
        const int idx = base + j;
        if (idx < N_NODES) {
            row_start[idx] = excl;
            cursor[idx] = excl;
            excl += counts[idx] + 1;
        }
    }
}

// ---------------------------------------------------------------------------
// K_lf: fused linear(MFMA) + CSR fill, block-interleaved ~1:4 so both kinds
// co-reside on every CU (fill's latency waits hide under linear's compute).
//   linear: 782 blocks -> h_bf16=x@Wg, z0(bf16)=bias+0.1*(x@Ws), att dots.
//   fill:   3321 blocks -> csr[atomic cursor slot]=src (+self-loops).
// ---------------------------------------------------------------------------
__global__ __launch_bounds__(256) void k_lf(
    const float* __restrict__ x,
    const unsigned short* __restrict__ Bfrag,
    const float* __restrict__ att_s,
    const float* __restrict__ att_d,
    const float* __restrict__ bias,
    unsigned short* __restrict__ h_bf, unsigned int* __restrict__ z0b,
    float* __restrict__ a_src, float* __restrict__ a_dst,
    const int* __restrict__ src, const int* __restrict__ dst,
    int* cursor, int* __restrict__ csr)
{
    const int bid = blockIdx.x;
    const int tid = threadIdx.x;
    const bool is_lin = (bid % 5 == 0) && (bid < 3910);

    if (!is_lin) {
        // ---------------- CSR fill ----------------
        const int fid = (bid < 3910) ? (bid - (bid + 4) / 5) : (bid - 782);
        const int i = fid * 256 + tid;
        if (i < N_EDGES + N_NODES) {
            int s, d;
            if (i < N_EDGES) { s = src[i]; d = dst[i]; }
            else             { s = d = i - N_EDGES; }   // self-loops
            const int slot = atomicAdd(&cursor[d], 1);
            csr[slot] = s;
        }
        return;
    }

    // ---------------- linear (MFMA) ----------------
    __shared__ unsigned short sA[16 * 64 * 8];   // [mt*4+kq][lane][j]  16 KB
    const int lin = bid / 5;
    const int lane = tid & 63;
    const int w = tid >> 6;
    const int nbase = lin * 64;

    // stage A: x[64 nodes][128 k] -> bf16 fragment-major
#pragma unroll
    for (int it = 0; it < 4; it++) {
        const int p = it * 256 + tid;
        const int node = p >> 4;        // 0..63
        const int kg = p & 15;          // k-group of 8
        const int gn = nbase + node;
        float v[8];
        if (gn < N_NODES) {
            float4 u0 = *(const float4*)(x + (size_t)gn * F_IN + kg * 8);
            float4 u1 = *(const float4*)(x + (size_t)gn * F_IN + kg * 8 + 4);
            v[0] = u0.x; v[1] = u0.y; v[2] = u0.z; v[3] = u0.w;
            v[4] = u1.x; v[5] = u1.y; v[6] = u1.z; v[7] = u1.w;
        } else {
#pragma unroll
            for (int j = 0; j < 8; j++) v[j] = 0.f;
        }
        const int mt = node >> 4, lm = node & 15;
        const int kq = kg >> 2, quad = kg & 3;
        uint4 pk;
        pk.x = f2bf(v[0]) | (f2bf(v[1]) << 16);
        pk.y = f2bf(v[2]) | (f2bf(v[3]) << 16);
        pk.z = f2bf(v[4]) | (f2bf(v[5]) << 16);
        pk.w = f2bf(v[6]) | (f2bf(v[7]) << 16);
        *(uint4*)(sA + ((size_t)((mt * 4 + kq) * 64 + quad * 16 + lm)) * 8) = pk;
    }
    __syncthreads();

    const bf16x8* Bf = (const bf16x8*)Bfrag;
    f32x4 acc[4][4];
#pragma unroll
    for (int mt = 0; mt < 4; mt++)
#pragma unroll
        for (int nt = 0; nt < 4; nt++)
            acc[mt][nt] = (f32x4){0.f, 0.f, 0.f, 0.f};

#pragma unroll
    for (int kq = 0; kq < 4; kq++) {
        bf16x8 aF[4], bF[4];
#pragma unroll
        for (int nt = 0; nt < 4; nt++)
            bF[nt] = Bf[(size_t)(((w * 4 + nt) * 4 + kq) * 64 + lane)];
#pragma unroll
        for (int mt = 0; mt < 4; mt++)
            aF[mt] = *(const bf16x8*)(sA + ((size_t)((mt * 4 + kq) * 64 + lane)) * 8);
#pragma unroll
        for (int mt = 0; mt < 4; mt++)
#pragma unroll
            for (int nt = 0; nt < 4; nt++)
                acc[mt][nt] = __builtin_amdgcn_mfma_f32_16x16x32_bf16(
                    aF[mt], bF[nt], acc[mt][nt], 0, 0, 0);
    }

    // epilogue: D[row=(lane>>4)*4+r][col=lane&15]
    const int row4 = (lane >> 4) * 4;
    const int cl = lane & 15;
#pragma unroll
    for (int mt = 0; mt < 4; mt++) {
#pragma unroll
        for (int nt = 0; nt < 4; nt++) {
            const int c = w * 64 + nt * 16 + cl;   // wave-uniform branch below
            f32x4 d = acc[mt][nt];
            if (c < 128) {
                const float asv = att_s[c];
                const float adv = att_d[c];
                float ps[4], pd[4];
#pragma unroll
                for (int r = 0; r < 4; r++) { ps[r] = d[r] * asv; pd[r] = d[r] * adv; }
#pragma unroll
                for (int m = 1; m <= 8; m <<= 1) {
#pragma unroll
                    for (int r = 0; r < 4; r++) {
                        ps[r] += __shfl_xor(ps[r], m);
                        pd[r] += __shfl_xor(pd[r], m);
                    }
                }
                const int head = w * 4 + nt;
#pragma unroll
                for (int r = 0; r < 4; r++) {
                    const int gn = nbase + mt * 16 + row4 + r;
                    if (gn < N_NODES) {
                        h_bf[(size_t)gn * HC + c] = (unsigned short)f2bf(d[r]);
                        if (cl == 0) {
                            a_src[gn * 8 + head] = ps[r];
                            a_dst[gn * 8 + head] = pd[r];
                        }
                    }
                }
            } else {
                const int cz = c - 128;
                const float bv = bias[cz];
#pragma unroll
                for (int r = 0; r < 4; r++) {
                    const int gn = nbase + mt * 16 + row4 + r;
                    const float val = 0.1f * d[r] + bv;
                    const float oth = __shfl_xor(val, 1);   // neighbor col
                    if ((cl & 1) == 0 && gn < N_NODES) {
                        z0b[(size_t)gn * 64 + (cz >> 1)] =
                            f2bf(val) | (f2bf(oth) << 16);
                    }
                }
            }
        }
    }
}

// ---------------------------------------------------------------------------
// K_agg: per-node aggregation + skip + LN + ELU.
// 2 nodes per wave (32 lanes, uint2 = 4 cols/lane); batch-4 gathers;
// tail edges weight-masked. cnt = counts[n]+1 (self-loop implicit).
// Softmax max-subtraction cancels in (sum w*h)/(sum w); |e| small -> no ovf.
// ---------------------------------------------------------------------------
__global__ __launch_bounds__(256) void k_agg(
    const uint2* __restrict__ h2,    // bf16 pairs, [N][32] uint2
    const uint2* __restrict__ z0b,   // bf16 pairs, [N][32] uint2
    const float* __restrict__ a_src, const float* __restrict__ a_dst,
    const int* __restrict__ row_start, const int* __restrict__ counts,
    const int* __restrict__ csr,
    const float* __restrict__ gamma, const float* __restrict__ beta,
    float* __restrict__ out)
{
    const int tid = threadIdx.x;
    const int lane = tid & 63;
    const int l = lane & 31;                 // lane within node-half
    const int n = blockIdx.x * 8 + ((tid >> 6) << 1) + (lane >> 5);
    const int head = l >> 2;                 // cols 4l..4l+3 share a head

    const float adn = a_dst[n * 8 + head];
    const int rs = row_start[n];
    const int cnt = counts[n] + 1;           // + self-loop

    float d_acc = 0.f, a0 = 0.f, a1 = 0.f, a2 = 0.f, a3 = 0.f;
    for (int i = 0; i < cnt; i += 4) {
        int s[4]; float ae[4], mk[4]; uint2 hp[4];
#pragma unroll
        for (int j = 0; j < 4; j++) {
            const int e = i + j;
            const int ec = (e < cnt) ? e : (cnt - 1);
            mk[j] = (e < cnt) ? 1.f : 0.f;
            s[j] = csr[rs + ec];
        }
#pragma unroll
        for (int j = 0; j < 4; j++) ae[j] = a_src[s[j] * 8 + head];
#pragma unroll
        for (int j = 0; j < 4; j++) hp[j] = h2[(size_t)s[j] * 32 + l];
#pragma unroll
        for (int j = 0; j < 4; j++) {
            float e = ae[j] + adn;
            e = (e > 0.f) ? e : 0.2f * e;      // leaky_relu(0.2)
            const float wgt = __expf(e) * mk[j];
            d_acc += wgt;
            a0 += wgt * bf2f(hp[j].x & 0xffffu);
            a1 += wgt * bf2f(hp[j].x >> 16);
            a2 += wgt * bf2f(hp[j].y & 0xffffu);
            a3 += wgt * bf2f(hp[j].y >> 16);
        }
    }
    const float inv = 1.0f / d_acc;
    const uint2 zp = z0b[(size_t)n * 32 + l];
    float y0 = a0 * inv + bf2f(zp.x & 0xffffu);
    float y1 = a1 * inv + bf2f(zp.x >> 16);
    float y2 = a2 * inv + bf2f(zp.y & 0xffffu);
    float y3 = a3 * inv + bf2f(zp.y >> 16);

    // LayerNorm over 128 cols (32-lane half-wave reduce)
    float ss = y0 + y1 + y2 + y3;
#pragma unroll
    for (int off = 1; off < 32; off <<= 1) ss += __shfl_xor(ss, off);
    const float mu = ss * (1.0f / 128.0f);
    const float d0 = y0 - mu, d1 = y1 - mu, d2 = y2 - mu, d3 = y3 - mu;
    float vs = d0 * d0 + d1 * d1 + d2 * d2 + d3 * d3;
#pragma unroll
    for (int off = 1; off < 32; off <<= 1) vs += __shfl_xor(vs, off);
    const float rstd = rsqrtf(vs * (1.0f / 128.0f) + 1e-5f);

    const float4 gv = *(const float4*)(gamma + l * 4);
    const float4 bv = *(const float4*)(beta + l * 4);
    float o0 = d0 * rstd * gv.x + bv.x;
    float o1 = d1 * rstd * gv.y + bv.y;
    float o2 = d2 * rstd * gv.z + bv.z;
    float o3 = d3 * rstd * gv.w + bv.w;
    o0 = (o0 > 0.f) ? o0 : (__expf(o0) - 1.0f);   // ELU
    o1 = (o1 > 0.f) ? o1 : (__expf(o1) - 1.0f);
    o2 = (o2 > 0.f) ? o2 : (__expf(o2) - 1.0f);
    o3 = (o3 > 0.f) ? o3 : (__expf(o3) - 1.0f);

    *(float4*)(out + (size_t)n * HC + l * 4) = make_float4(o0, o1, o2, o3);
}

// ---------------------------------------------------------------------------
extern "C" void kernel_launch(void* const* d_in, const int* in_sizes, int n_in,
                              void* d_out, int out_size, void* d_ws, size_t ws_size,
                              hipStream_t stream) {
    const float* x   = (const float*)d_in[0];
    const int*   ei  = (const int*)d_in[1];
    const float* Wg  = (const float*)d_in[2];
    const float* as_ = (const float*)d_in[3];
    const float* ad_ = (const float*)d_in[4];
    const float* bg  = (const float*)d_in[5];
    const float* Wsk = (const float*)d_in[6];
    const float* gm  = (const float*)d_in[7];
    const float* bt  = (const float*)d_in[8];
    float* out = (float*)d_out;

    // workspace layout (bytes), ~32.9 MB total
    char* wsb = (char*)d_ws;
    unsigned short* h_bf  = (unsigned short*)wsb;              // [N][128] bf16
    unsigned int*   z0b   = (unsigned int*)(wsb + 12800000);   // [N][64] bf16x2
    float*          a_src = (float*)(wsb + 25600000);          // [N][8]
    float*          a_dst = (float*)(wsb + 27200000);          // [N][8]
    unsigned short* Bfrag = (unsigned short*)(wsb + 28800000); // 64 KB
    int*   counts = (int*)(wsb + 28865536);                    // 50048
    int*   row_st = (int*)(wsb + 29065728);
    int*   cursor = (int*)(wsb + 29265920);
    int*   csr    = (int*)(wsb + 29466112);                    // 850000

    const int* src = ei;
    const int* dst = ei + N_EDGES;

    hipMemsetAsync(counts, 0, 50048 * sizeof(int), stream);
    k_pc  <<<3141, 256, 0, stream>>>(dst, Wg, Wsk, Bfrag, counts);
    k_scan<<<1, 1024, 0, stream>>>(counts, row_st, cursor);
    k_lf  <<<4103, 256, 0, stream>>>(x, Bfrag, as_, ad_, bg, h_bf, z0b,
                                     a_src, a_dst, src, dst, cursor, csr);
    k_agg <<<N_NODES / 8, 256, 0, stream>>>((const uint2*)h_bf, (const uint2*)z0b,
                                            a_src, a_dst, row_st, counts, csr,
                                            gm, bt, out);
}

// Round 6
// 226.593 us; speedup vs baseline: 1.4893x; 1.4893x over previous
//
#include <hip/hip_runtime.h>
#include <hip/hip_bf16.h>

#define N_NODES 50000
#define N_EDGES 800000
#define F_IN    128
#define HC      128      // H*C

typedef __attribute__((ext_vector_type(8))) short bf16x8;
typedef __attribute__((ext_vector_type(4))) float f32x4;

__device__ __forceinline__ float bf2f(unsigned int u16) {
    return __uint_as_float(u16 << 16);
}
__device__ __forceinline__ unsigned int f2bf(float f) {
    unsigned int u = __float_as_uint(f);
    return (u + 0x7fffu + ((u >> 16) & 1u)) >> 16;   // RNE
}

// ---------------------------------------------------------------------------
// K_pc: fused. Blocks 0..3124: edge-count atomics (counts pre-zeroed by
// memset; self-loop +1 folded into the scan). Blocks 3125..3140: pack
// [Wg|Ws] into MFMA-B fragment-major bf16 (slot g=(nt*4+kq)*64+lane holds
// W[kq*32+(lane>>4)*8+j][nt*16+(lane&15)]; cols 0..127=Wg, 128..255=Ws).
// ---------------------------------------------------------------------------
__global__ __launch_bounds__(256) void k_pc(
    const int* __restrict__ dst,
    const float* __restrict__ Wg, const float* __restrict__ Ws,
    unsigned short* __restrict__ Bfrag, int* __restrict__ counts)
{
    const int bid = blockIdx.x;
    if (bid < 3125) {
        const int i = bid * 256 + threadIdx.x;
        if (i < N_EDGES) atomicAdd(&counts[dst[i]], 1);
    } else {
        const int g = (bid - 3125) * 256 + threadIdx.x;
        if (g < 4096) {
            const int lane = g & 63;
            const int kq = (g >> 6) & 3;
            const int nt = g >> 8;           // 0..15
            const int c = nt * 16 + (lane & 15);
            const int kbase = kq * 32 + (lane >> 4) * 8;
            const float* Wsel = (c < 128) ? (Wg + c) : (Ws + c - 128);
            unsigned int pk[4];
#pragma unroll
            for (int p = 0; p < 4; p++) {
                const float v0 = Wsel[(size_t)(kbase + 2 * p) * HC];
                const float v1 = Wsel[(size_t)(kbase + 2 * p + 1) * HC];
                pk[p] = f2bf(v0) | (f2bf(v1) << 16);
            }
            *(uint4*)(Bfrag + (size_t)g * 8) = make_uint4(pk[0], pk[1], pk[2], pk[3]);
        }
    }
}

// ---------------------------------------------------------------------------
// Hierarchical exclusive scan of (counts[i]+1): scanA (49 blocks x 1024
// elems) -> scanB (one wave over 49 block sums) -> scanC (apply + cursor).
// Multi-block on purpose: the single-block variant ran at 0.15% occupancy
// and cost 124 us (R5 regression).
// ---------------------------------------------------------------------------
__global__ __launch_bounds__(256) void k_scanA(const int* __restrict__ counts,
                                               int* __restrict__ row_start,
                                               int* __restrict__ bsum) {
    __shared__ int s[256];
    const int tid = threadIdx.x;
    const int base = blockIdx.x * 1024 + tid * 4;
    int v[4]; int t = 0;
#pragma unroll
    for (int j = 0; j < 4; j++) {
        int idx = base + j;
        v[j] = (idx < N_NODES) ? (counts[idx] + 1) : 0;   // +1 = self-loop
        t += v[j];
    }
    s[tid] = t;
    __syncthreads();
    for (int off = 1; off < 256; off <<= 1) {
        int add = (tid >= off) ? s[tid - off] : 0;
        __syncthreads();
        s[tid] += add;
        __syncthreads();
    }
    int excl = s[tid] - t;
#pragma unroll
    for (int j = 0; j < 4; j++) {
        int idx = base + j;
        if (idx < N_NODES) row_start[idx] = excl;
        excl += v[j];
    }
    if (tid == 255) bsum[blockIdx.x] = s[255];
}

__global__ void k_scanB(int* bsum, int nb) {
    int tid = threadIdx.x;   // 64 threads, nb <= 64
    int v = (tid < nb) ? bsum[tid] : 0;
    int orig = v;
    for (int off = 1; off < 64; off <<= 1) {
        int y = __shfl_up(v, off);
        if (tid >= off) v += y;
    }
    if (tid < nb) bsum[tid] = v - orig;   // exclusive block offsets
}

__global__ void k_scanC(int* __restrict__ row_start, const int* __restrict__ bsum,
                        int* __restrict__ cursor) {
    int i = blockIdx.x * 256 + threadIdx.x;
    if (i < N_NODES) {
        int rs = row_start[i] + bsum[i >> 10];
        row_start[i] = rs;
        cursor[i] = rs;
    }
}

// ---------------------------------------------------------------------------
// K_lf: fused linear(MFMA) + CSR fill, block-interleaved ~1:4 so both kinds
// co-reside on every CU (fill's latency waits hide under linear's compute).
//   linear: 782 blocks -> h_bf16=x@Wg, z0(bf16)=bias+0.1*(x@Ws), att dots.
//   fill:   3321 blocks -> csr[atomic cursor slot]=src (+self-loops).
// ---------------------------------------------------------------------------
__global__ __launch_bounds__(256) void k_lf(
    const float* __restrict__ x,
    const unsigned short* __restrict__ Bfrag,
    const float* __restrict__ att_s,
    const float* __restrict__ att_d,
    const float* __restrict__ bias,
    unsigned short* __restrict__ h_bf, unsigned int* __restrict__ z0b,
    float* __restrict__ a_src, float* __restrict__ a_dst,
    const int* __restrict__ src, const int* __restrict__ dst,
    int* cursor, int* __restrict__ csr)
{
    const int bid = blockIdx.x;
    const int tid = threadIdx.x;
    const bool is_lin = (bid % 5 == 0) && (bid < 3910);

    if (!is_lin) {
        // ---------------- CSR fill ----------------
        const int fid = (bid < 3910) ? (bid - (bid + 4) / 5) : (bid - 782);
        const int i = fid * 256 + tid;
        if (i < N_EDGES + N_NODES) {
            int s, d;
            if (i < N_EDGES) { s = src[i]; d = dst[i]; }
            else             { s = d = i - N_EDGES; }   // self-loops
            const int slot = atomicAdd(&cursor[d], 1);
            csr[slot] = s;
        }
        return;
    }

    // ---------------- linear (MFMA) ----------------
    __shared__ unsigned short sA[16 * 64 * 8];   // [mt*4+kq][lane][j]  16 KB
    const int lin = bid / 5;
    const int lane = tid & 63;
    const int w = tid >> 6;
    const int nbase = lin * 64;

    // stage A: x[64 nodes][128 k] -> bf16 fragment-major
#pragma unroll
    for (int it = 0; it < 4; it++) {
        const int p = it * 256 + tid;
        const int node = p >> 4;        // 0..63
        const int kg = p & 15;          // k-group of 8
        const int gn = nbase + node;
        float v[8];
        if (gn < N_NODES) {
            float4 u0 = *(const float4*)(x + (size_t)gn * F_IN + kg * 8);
            float4 u1 = *(const float4*)(x + (size_t)gn * F_IN + kg * 8 + 4);
            v[0] = u0.x; v[1] = u0.y; v[2] = u0.z; v[3] = u0.w;
            v[4] = u1.x; v[5] = u1.y; v[6] = u1.z; v[7] = u1.w;
        } else {
#pragma unroll
            for (int j = 0; j < 8; j++) v[j] = 0.f;
        }
        const int mt = node >> 4, lm = node & 15;
        const int kq = kg >> 2, quad = kg & 3;
        uint4 pk;
        pk.x = f2bf(v[0]) | (f2bf(v[1]) << 16);
        pk.y = f2bf(v[2]) | (f2bf(v[3]) << 16);
        pk.z = f2bf(v[4]) | (f2bf(v[5]) << 16);
        pk.w = f2bf(v[6]) | (f2bf(v[7]) << 16);
        *(uint4*)(sA + ((size_t)((mt * 4 + kq) * 64 + quad * 16 + lm)) * 8) = pk;
    }
    __syncthreads();

    const bf16x8* Bf = (const bf16x8*)Bfrag;
    f32x4 acc[4][4];
#pragma unroll
    for (int mt = 0; mt < 4; mt++)
#pragma unroll
        for (int nt = 0; nt < 4; nt++)
            acc[mt][nt] = (f32x4){0.f, 0.f, 0.f, 0.f};

#pragma unroll
    for (int kq = 0; kq < 4; kq++) {
        bf16x8 aF[4], bF[4];
#pragma unroll
        for (int nt = 0; nt < 4; nt++)
            bF[nt] = Bf[(size_t)(((w * 4 + nt) * 4 + kq) * 64 + lane)];
#pragma unroll
        for (int mt = 0; mt < 4; mt++)
            aF[mt] = *(const bf16x8*)(sA + ((size_t)((mt * 4 + kq) * 64 + lane)) * 8);
#pragma unroll
        for (int mt = 0; mt < 4; mt++)
#pragma unroll
            for (int nt = 0; nt < 4; nt++)
                acc[mt][nt] = __builtin_amdgcn_mfma_f32_16x16x32_bf16(
                    aF[mt], bF[nt], acc[mt][nt], 0, 0, 0);
    }

    // epilogue: D[row=(lane>>4)*4+r][col=lane&15]
    const int row4 = (lane >> 4) * 4;
    const int cl = lane & 15;
#pragma unroll
    for (int mt = 0; mt < 4; mt++) {
#pragma unroll
        for (int nt = 0; nt < 4; nt++) {
            const int c = w * 64 + nt * 16 + cl;   // wave-uniform branch below
            f32x4 d = acc[mt][nt];
            if (c < 128) {
                const float asv = att_s[c];
                const float adv = att_d[c];
                float ps[4], pd[4];
#pragma unroll
                for (int r = 0; r < 4; r++) { ps[r] = d[r] * asv; pd[r] = d[r] * adv; }
#pragma unroll
                for (int m = 1; m <= 8; m <<= 1) {
#pragma unroll
                    for (int r = 0; r < 4; r++) {
                        ps[r] += __shfl_xor(ps[r], m);
                        pd[r] += __shfl_xor(pd[r], m);
                    }
                }
                const int head = w * 4 + nt;
#pragma unroll
                for (int r = 0; r < 4; r++) {
                    const int gn = nbase + mt * 16 + row4 + r;
                    if (gn < N_NODES) {
                        h_bf[(size_t)gn * HC + c] = (unsigned short)f2bf(d[r]);
                        if (cl == 0) {
                            a_src[gn * 8 + head] = ps[r];
                            a_dst[gn * 8 + head] = pd[r];
                        }
                    }
                }
            } else {
                const int cz = c - 128;
                const float bv = bias[cz];
#pragma unroll
                for (int r = 0; r < 4; r++) {
                    const int gn = nbase + mt * 16 + row4 + r;
                    const float val = 0.1f * d[r] + bv;
                    const float oth = __shfl_xor(val, 1);   // neighbor col
                    if ((cl & 1) == 0 && gn < N_NODES) {
                        z0b[(size_t)gn * 64 + (cz >> 1)] =
                            f2bf(val) | (f2bf(oth) << 16);
                    }
                }
            }
        }
    }
}

// ---------------------------------------------------------------------------
// K_agg: per-node aggregation + skip + LN + ELU.
// 2 nodes per wave (32 lanes, uint2 = 4 cols/lane); batch-4 gathers;
// tail edges weight-masked. cnt = counts[n]+1 (self-loop implicit).
// Softmax max-subtraction cancels in (sum w*h)/(sum w); |e| small -> no ovf.
// ---------------------------------------------------------------------------
__global__ __launch_bounds__(256) void k_agg(
    const uint2* __restrict__ h2,    // bf16 pairs, [N][32] uint2
    const uint2* __restrict__ z0b,   // bf16 pairs, [N][32] uint2
    const float* __restrict__ a_src, const float* __restrict__ a_dst,
    const int* __restrict__ row_start, const int* __restrict__ counts,
    const int* __restrict__ csr,
    const float* __restrict__ gamma, const float* __restrict__ beta,
    float* __restrict__ out)
{
    const int tid = threadIdx.x;
    const int lane = tid & 63;
    const int l = lane & 31;                 // lane within node-half
    const int n = blockIdx.x * 8 + ((tid >> 6) << 1) + (lane >> 5);
    const int head = l >> 2;                 // cols 4l..4l+3 share a head

    const float adn = a_dst[n * 8 + head];
    const int rs = row_start[n];
    const int cnt = counts[n] + 1;           // + self-loop

    float d_acc = 0.f, a0 = 0.f, a1 = 0.f, a2 = 0.f, a3 = 0.f;
    for (int i = 0; i < cnt; i += 4) {
        int s[4]; float ae[4], mk[4]; uint2 hp[4];
#pragma unroll
        for (int j = 0; j < 4; j++) {
            const int e = i + j;
            const int ec = (e < cnt) ? e : (cnt - 1);
            mk[j] = (e < cnt) ? 1.f : 0.f;
            s[j] = csr[rs + ec];
        }
#pragma unroll
        for (int j = 0; j < 4; j++) ae[j] = a_src[s[j] * 8 + head];
#pragma unroll
        for (int j = 0; j < 4; j++) hp[j] = h2[(size_t)s[j] * 32 + l];
#pragma unroll
        for (int j = 0; j < 4; j++) {
            float e = ae[j] + adn;
            e = (e > 0.f) ? e : 0.2f * e;      // leaky_relu(0.2)
            const float wgt = __expf(e) * mk[j];
            d_acc += wgt;
            a0 += wgt * bf2f(hp[j].x & 0xffffu);
            a1 += wgt * bf2f(hp[j].x >> 16);
            a2 += wgt * bf2f(hp[j].y & 0xffffu);
            a3 += wgt * bf2f(hp[j].y >> 16);
        }
    }
    const float inv = 1.0f / d_acc;
    const uint2 zp = z0b[(size_t)n * 32 + l];
    float y0 = a0 * inv + bf2f(zp.x & 0xffffu);
    float y1 = a1 * inv + bf2f(zp.x >> 16);
    float y2 = a2 * inv + bf2f(zp.y & 0xffffu);
    float y3 = a3 * inv + bf2f(zp.y >> 16);

    // LayerNorm over 128 cols (32-lane half-wave reduce)
    float ss = y0 + y1 + y2 + y3;
#pragma unroll
    for (int off = 1; off < 32; off <<= 1) ss += __shfl_xor(ss, off);
    const float mu = ss * (1.0f / 128.0f);
    const float d0 = y0 - mu, d1 = y1 - mu, d2 = y2 - mu, d3 = y3 - mu;
    float vs = d0 * d0 + d1 * d1 + d2 * d2 + d3 * d3;
#pragma unroll
    for (int off = 1; off < 32; off <<= 1) vs += __shfl_xor(vs, off);
    const float rstd = rsqrtf(vs * (1.0f / 128.0f) + 1e-5f);

    const float4 gv = *(const float4*)(gamma + l * 4);
    const float4 bv = *(const float4*)(beta + l * 4);
    float o0 = d0 * rstd * gv.x + bv.x;
    float o1 = d1 * rstd * gv.y + bv.y;
    float o2 = d2 * rstd * gv.z + bv.z;
    float o3 = d3 * rstd * gv.w + bv.w;
    o0 = (o0 > 0.f) ? o0 : (__expf(o0) - 1.0f);   // ELU
    o1 = (o1 > 0.f) ? o1 : (__expf(o1) - 1.0f);
    o2 = (o2 > 0.f) ? o2 : (__expf(o2) - 1.0f);
    o3 = (o3 > 0.f) ? o3 : (__expf(o3) - 1.0f);

    *(float4*)(out + (size_t)n * HC + l * 4) = make_float4(o0, o1, o2, o3);
}

// ---------------------------------------------------------------------------
extern "C" void kernel_launch(void* const* d_in, const int* in_sizes, int n_in,
                              void* d_out, int out_size, void* d_ws, size_t ws_size,
                              hipStream_t stream) {
    const float* x   = (const float*)d_in[0];
    const int*   ei  = (const int*)d_in[1];
    const float* Wg  = (const float*)d_in[2];
    const float* as_ = (const float*)d_in[3];
    const float* ad_ = (const float*)d_in[4];
    const float* bg  = (const float*)d_in[5];
    const float* Wsk = (const float*)d_in[6];
    const float* gm  = (const float*)d_in[7];
    const float* bt  = (const float*)d_in[8];
    float* out = (float*)d_out;

    // workspace layout (bytes), ~33 MB total
    char* wsb = (char*)d_ws;
    unsigned short* h_bf  = (unsigned short*)wsb;              // [N][128] bf16
    unsigned int*   z0b   = (unsigned int*)(wsb + 12800000);   // [N][64] bf16x2
    float*          a_src = (float*)(wsb + 25600000);          // [N][8]
    float*          a_dst = (float*)(wsb + 27200000);          // [N][8]
    unsigned short* Bfrag = (unsigned short*)(wsb + 28800000); // 64 KB
    int*   counts = (int*)(wsb + 28865536);                    // 50048
    int*   row_st = (int*)(wsb + 29065728);
    int*   cursor = (int*)(wsb + 29265920);
    int*   bsum   = (int*)(wsb + 29466112);                    // 256
    int*   csr    = (int*)(wsb + 29467136);                    // 850000

    const int* src = ei;
    const int* dst = ei + N_EDGES;

    hipMemsetAsync(counts, 0, 50048 * sizeof(int), stream);
    k_pc   <<<3141, 256, 0, stream>>>(dst, Wg, Wsk, Bfrag, counts);
    k_scanA<<<49, 256, 0, stream>>>(counts, row_st, bsum);
    k_scanB<<<1, 64, 0, stream>>>(bsum, 49);
    k_scanC<<<(N_NODES + 255) / 256, 256, 0, stream>>>(row_st, bsum, cursor);
    k_lf   <<<4103, 256, 0, stream>>>(x, Bfrag, as_, ad_, bg, h_bf, z0b,
                                      a_src, a_dst, src, dst, cursor, csr);
    k_agg  <<<N_NODES / 8, 256, 0, stream>>>((const uint2*)h_bf, (const uint2*)z0b,
                                             a_src, a_dst, row_st, counts, csr,
                                             gm, bt, out);
}

// Round 7
// 213.167 us; speedup vs baseline: 1.5831x; 1.0630x over previous
//
#include <hip/hip_runtime.h>
#include <hip/hip_bf16.h>

#define N_NODES 50000
#define N_EDGES 800000
#define F_IN    128
#define HC      128      // H*C
#define NR      8        // node ranges (XCD-pinned)
#define RSZ     6250     // nodes per range
#define NCH     16       // edge chunks
#define CHSZ    50000    // edges per chunk

typedef __attribute__((ext_vector_type(8))) short bf16x8;
typedef __attribute__((ext_vector_type(4))) float f32x4;

__device__ __forceinline__ float bf2f(unsigned int u16) {
    return __uint_as_float(u16 << 16);
}
__device__ __forceinline__ unsigned int f2bf(float f) {
    unsigned int u = __float_as_uint(f);
    return (u + 0x7fffu + ((u >> 16) & 1u)) >> 16;   // RNE
}

// ---------------------------------------------------------------------------
// K_hist: blocks 0..127 = LDS sub-histogram for (range r = bid&7, chunk
// c = bid>>3): stream 50K dsts, LDS-atomic count those in [r*RSZ,(r+1)*RSZ),
// write partials to part[node*16+c] (full-line aggregation in XCD-r L2 via
// bid%8=r pinning heuristic). Blocks 128..143: pack [Wg|Ws] -> Bfrag
// (MFMA-B fragment-major bf16). NO global atomics.
// ---------------------------------------------------------------------------
__global__ __launch_bounds__(256) void k_hist(
    const int* __restrict__ dst,
    const float* __restrict__ Wg, const float* __restrict__ Ws,
    unsigned short* __restrict__ Bfrag, int* __restrict__ part)
{
    const int bid = blockIdx.x;
    const int tid = threadIdx.x;
    if (bid < 128) {
        __shared__ int hist[RSZ];
        const int r = bid & 7, c = bid >> 3;
        const int nb = r * RSZ;
        for (int i = tid; i < RSZ; i += 256) hist[i] = 0;
        __syncthreads();
        const int4* d4 = (const int4*)(dst + c * CHSZ);
        for (int i = tid; i < CHSZ / 4; i += 256) {
            const int4 v = d4[i];
            int b;
            b = v.x - nb; if ((unsigned)b < (unsigned)RSZ) atomicAdd(&hist[b], 1);
            b = v.y - nb; if ((unsigned)b < (unsigned)RSZ) atomicAdd(&hist[b], 1);
            b = v.z - nb; if ((unsigned)b < (unsigned)RSZ) atomicAdd(&hist[b], 1);
            b = v.w - nb; if ((unsigned)b < (unsigned)RSZ) atomicAdd(&hist[b], 1);
        }
        __syncthreads();
        for (int i = tid; i < RSZ; i += 256)
            part[(size_t)(nb + i) * NCH + c] = hist[i];
    } else {
        const int g = (bid - 128) * 256 + tid;
        if (g < 4096) {
            const int lane = g & 63;
            const int kq = (g >> 6) & 3;
            const int nt = g >> 8;           // 0..15
            const int cc = nt * 16 + (lane & 15);
            const int kbase = kq * 32 + (lane >> 4) * 8;
            const float* Wsel = (cc < 128) ? (Wg + cc) : (Ws + cc - 128);
            unsigned int pk[4];
#pragma unroll
            for (int p = 0; p < 4; p++) {
                const float v0 = Wsel[(size_t)(kbase + 2 * p) * HC];
                const float v1 = Wsel[(size_t)(kbase + 2 * p + 1) * HC];
                pk[p] = f2bf(v0) | (f2bf(v1) << 16);
            }
            *(uint4*)(Bfrag + (size_t)g * 8) = make_uint4(pk[0], pk[1], pk[2], pk[3]);
        }
    }
}

// ---------------------------------------------------------------------------
// K_merge: per node, sum the 16 chunk partials -> counts[n]; replace
// part[n*16+c] with the chunk-exclusive prefix (deterministic fill slots).
// Fully coalesced 64B line per thread.
// ---------------------------------------------------------------------------
__global__ __launch_bounds__(256) void k_merge(int* __restrict__ part,
                                               int* __restrict__ counts)
{
    const int n = blockIdx.x * 256 + threadIdx.x;
    if (n >= N_NODES) return;
    int4* p = (int4*)(part + (size_t)n * NCH);
    int4 v0 = p[0], v1 = p[1], v2 = p[2], v3 = p[3];
    int vv[16] = {v0.x, v0.y, v0.z, v0.w, v1.x, v1.y, v1.z, v1.w,
                  v2.x, v2.y, v2.z, v2.w, v3.x, v3.y, v3.z, v3.w};
    int run = 0;
#pragma unroll
    for (int c = 0; c < 16; c++) { const int t = vv[c]; vv[c] = run; run += t; }
    counts[n] = run;
    p[0] = make_int4(vv[0], vv[1], vv[2], vv[3]);
    p[1] = make_int4(vv[4], vv[5], vv[6], vv[7]);
    p[2] = make_int4(vv[8], vv[9], vv[10], vv[11]);
    p[3] = make_int4(vv[12], vv[13], vv[14], vv[15]);
}

// ---------------------------------------------------------------------------
// Hierarchical exclusive scan of (counts[i]+1). Multi-block on purpose:
// the single-block variant ran at 0.15% occupancy, 124 us (R5 regression).
// ---------------------------------------------------------------------------
__global__ __launch_bounds__(256) void k_scanA(const int* __restrict__ counts,
                                               int* __restrict__ row_start,
                                               int* __restrict__ bsum) {
    __shared__ int s[256];
    const int tid = threadIdx.x;
    const int base = blockIdx.x * 1024 + tid * 4;
    int v[4]; int t = 0;
#pragma unroll
    for (int j = 0; j < 4; j++) {
        int idx = base + j;
        v[j] = (idx < N_NODES) ? (counts[idx] + 1) : 0;   // +1 = self-loop
        t += v[j];
    }
    s[tid] = t;
    __syncthreads();
    for (int off = 1; off < 256; off <<= 1) {
        int add = (tid >= off) ? s[tid - off] : 0;
        __syncthreads();
        s[tid] += add;
        __syncthreads();
    }
    int excl = s[tid] - t;
#pragma unroll
    for (int j = 0; j < 4; j++) {
        int idx = base + j;
        if (idx < N_NODES) row_start[idx] = excl;
        excl += v[j];
    }
    if (tid == 255) bsum[blockIdx.x] = s[255];
}

__global__ void k_scanB(int* bsum, int nb) {
    int tid = threadIdx.x;   // 64 threads, nb <= 64
    int v = (tid < nb) ? bsum[tid] : 0;
    int orig = v;
    for (int off = 1; off < 64; off <<= 1) {
        int y = __shfl_up(v, off);
        if (tid >= off) v += y;
    }
    if (tid < nb) bsum[tid] = v - orig;   // exclusive block offsets
}

// scanC: finalize row_start and write each node's self-loop into its LAST
// csr slot (slot rs+counts[i]; edge slots occupy rs..rs+counts[i]-1).
__global__ void k_scanC(int* __restrict__ row_start, const int* __restrict__ bsum,
                        const int* __restrict__ counts, int* __restrict__ csr) {
    int i = blockIdx.x * 256 + threadIdx.x;
    if (i < N_NODES) {
        int rs = row_start[i] + bsum[i >> 10];
        row_start[i] = rs;
        csr[rs + counts[i]] = i;
    }
}

// ---------------------------------------------------------------------------
// K_lf: fused linear(MFMA) + deterministic CSR fill.
// Fill blocks (r,c): LDS cursors = row_start + part-exclusive; stream chunk
// c's (src,dst); LDS-atomic rank -> scatter-store csr in range r's slice
// (XCD-pinned via bid%8=r so lines aggregate in one L2). No global atomics.
// Linear blocks: h_bf16=x@Wg, z0(bf16)=bias+0.1*(x@Ws), att dots.
// ---------------------------------------------------------------------------
__global__ __launch_bounds__(256) void k_lf(
    const float* __restrict__ x,
    const unsigned short* __restrict__ Bfrag,
    const float* __restrict__ att_s,
    const float* __restrict__ att_d,
    const float* __restrict__ bias,
    unsigned short* __restrict__ h_bf, unsigned int* __restrict__ z0b,
    float* __restrict__ a_src, float* __restrict__ a_dst,
    const int* __restrict__ src, const int* __restrict__ dst,
    const int* __restrict__ row_start, const int* __restrict__ part,
    int* __restrict__ csr)
{
    __shared__ __align__(16) int smem[RSZ];   // fill: cursors; linear: sA alias
    const int bid = blockIdx.x;
    const int tid = threadIdx.x;
    int lin = -1, r = 0, c = 0;
    if (bid < 256) {
        const int g = bid >> 4, pos = bid & 15;
        if (pos < 8) { r = pos; c = g; }           // bid%8 == r  (XCD pin)
        else lin = g * 8 + (pos - 8);
    } else {
        lin = 128 + (bid - 256);
    }

    if (lin < 0) {
        // ---------------- CSR fill ----------------
        const int nb = r * RSZ;
        for (int b = tid; b < RSZ; b += 256)
            smem[b] = row_start[nb + b] + part[(size_t)(nb + b) * NCH + c];
        __syncthreads();
        const int4* d4 = (const int4*)(dst + c * CHSZ);
        const int4* s4 = (const int4*)(src + c * CHSZ);
        for (int i = tid; i < CHSZ / 4; i += 256) {
            const int4 dv = d4[i];
            const int4 sv = s4[i];
            int b;
            b = dv.x - nb; if ((unsigned)b < (unsigned)RSZ) csr[atomicAdd(&smem[b], 1)] = sv.x;
            b = dv.y - nb; if ((unsigned)b < (unsigned)RSZ) csr[atomicAdd(&smem[b], 1)] = sv.y;
            b = dv.z - nb; if ((unsigned)b < (unsigned)RSZ) csr[atomicAdd(&smem[b], 1)] = sv.z;
            b = dv.w - nb; if ((unsigned)b < (unsigned)RSZ) csr[atomicAdd(&smem[b], 1)] = sv.w;
        }
        return;
    }

    // ---------------- linear (MFMA) ----------------
    unsigned short* sA = (unsigned short*)smem;   // [mt*4+kq][lane][j] 16 KB
    const int lane = tid & 63;
    const int w = tid >> 6;
    const int nbase = lin * 64;

    // stage A: x[64 nodes][128 k] -> bf16 fragment-major
#pragma unroll
    for (int it = 0; it < 4; it++) {
        const int p = it * 256 + tid;
        const int node = p >> 4;        // 0..63
        const int kg = p & 15;          // k-group of 8
        const int gn = nbase + node;
        float v[8];
        if (gn < N_NODES) {
            float4 u0 = *(const float4*)(x + (size_t)gn * F_IN + kg * 8);
            float4 u1 = *(const float4*)(x + (size_t)gn * F_IN + kg * 8 + 4);
            v[0] = u0.x; v[1] = u0.y; v[2] = u0.z; v[3] = u0.w;
            v[4] = u1.x; v[5] = u1.y; v[6] = u1.z; v[7] = u1.w;
        } else {
#pragma unroll
            for (int j = 0; j < 8; j++) v[j] = 0.f;
        }
        const int mt = node >> 4, lm = node & 15;
        const int kq = kg >> 2, quad = kg & 3;
        uint4 pk;
        pk.x = f2bf(v[0]) | (f2bf(v[1]) << 16);
        pk.y = f2bf(v[2]) | (f2bf(v[3]) << 16);
        pk.z = f2bf(v[4]) | (f2bf(v[5]) << 16);
        pk.w = f2bf(v[6]) | (f2bf(v[7]) << 16);
        *(uint4*)(sA + ((size_t)((mt * 4 + kq) * 64 + quad * 16 + lm)) * 8) = pk;
    }
    __syncthreads();

    const bf16x8* Bf = (const bf16x8*)Bfrag;
    f32x4 acc[4][4];
#pragma unroll
    for (int mt = 0; mt < 4; mt++)
#pragma unroll
        for (int nt = 0; nt < 4; nt++)
            acc[mt][nt] = (f32x4){0.f, 0.f, 0.f, 0.f};

#pragma unroll
    for (int kq = 0; kq < 4; kq++) {
        bf16x8 aF[4], bF[4];
#pragma unroll
        for (int nt = 0; nt < 4; nt++)
            bF[nt] = Bf[(size_t)(((w * 4 + nt) * 4 + kq) * 64 + lane)];
#pragma unroll
        for (int mt = 0; mt < 4; mt++)
            aF[mt] = *(const bf16x8*)(sA + ((size_t)((mt * 4 + kq) * 64 + lane)) * 8);
#pragma unroll
        for (int mt = 0; mt < 4; mt++)
#pragma unroll
            for (int nt = 0; nt < 4; nt++)
                acc[mt][nt] = __builtin_amdgcn_mfma_f32_16x16x32_bf16(
                    aF[mt], bF[nt], acc[mt][nt], 0, 0, 0);
    }

    // epilogue: D[row=(lane>>4)*4+r][col=lane&15]
    const int row4 = (lane >> 4) * 4;
    const int cl = lane & 15;
#pragma unroll
    for (int mt = 0; mt < 4; mt++) {
#pragma unroll
        for (int nt = 0; nt < 4; nt++) {
            const int cc = w * 64 + nt * 16 + cl;   // wave-uniform branch below
            f32x4 d = acc[mt][nt];
            if (cc < 128) {
                const float asv = att_s[cc];
                const float adv = att_d[cc];
                float ps[4], pd[4];
#pragma unroll
                for (int rr = 0; rr < 4; rr++) { ps[rr] = d[rr] * asv; pd[rr] = d[rr] * adv; }
#pragma unroll
                for (int m = 1; m <= 8; m <<= 1) {
#pragma unroll
                    for (int rr = 0; rr < 4; rr++) {
                        ps[rr] += __shfl_xor(ps[rr], m);
                        pd[rr] += __shfl_xor(pd[rr], m);
                    }
                }
                const int head = w * 4 + nt;
#pragma unroll
                for (int rr = 0; rr < 4; rr++) {
                    const int gn = nbase + mt * 16 + row4 + rr;
                    if (gn < N_NODES) {
                        h_bf[(size_t)gn * HC + cc] = (unsigned short)f2bf(d[rr]);
                        if (cl == 0) {
                            a_src[gn * 8 + head] = ps[rr];
                            a_dst[gn * 8 + head] = pd[rr];
                        }
                    }
                }
            } else {
                const int cz = cc - 128;
                const float bv = bias[cz];
#pragma unroll
                for (int rr = 0; rr < 4; rr++) {
                    const int gn = nbase + mt * 16 + row4 + rr;
                    const float val = 0.1f * d[rr] + bv;
                    const float oth = __shfl_xor(val, 1);   // neighbor col
                    if ((cl & 1) == 0 && gn < N_NODES) {
                        z0b[(size_t)gn * 64 + (cz >> 1)] =
                            f2bf(val) | (f2bf(oth) << 16);
                    }
                }
            }
        }
    }
}

// ---------------------------------------------------------------------------
// K_agg: per-node aggregation + skip + LN + ELU.
// 2 nodes per wave (32 lanes, uint2 = 4 cols/lane); batch-4 gathers;
// tail edges weight-masked. cnt = counts[n]+1 (self-loop = last slot).
// Softmax max-subtraction cancels in (sum w*h)/(sum w); |e| small -> no ovf.
// ---------------------------------------------------------------------------
__global__ __launch_bounds__(256) void k_agg(
    const uint2* __restrict__ h2,    // bf16 pairs, [N][32] uint2
    const uint2* __restrict__ z0b,   // bf16 pairs, [N][32] uint2
    const float* __restrict__ a_src, const float* __restrict__ a_dst,
    const int* __restrict__ row_start, const int* __restrict__ counts,
    const int* __restrict__ csr,
    const float* __restrict__ gamma, const float* __restrict__ beta,
    float* __restrict__ out)
{
    const int tid = threadIdx.x;
    const int lane = tid & 63;
    const int l = lane & 31;                 // lane within node-half
    const int n = blockIdx.x * 8 + ((tid >> 6) << 1) + (lane >> 5);
    const int head = l >> 2;                 // cols 4l..4l+3 share a head

    const float adn = a_dst[n * 8 + head];
    const int rs = row_start[n];
    const int cnt = counts[n] + 1;           // + self-loop

    float d_acc = 0.f, a0 = 0.f, a1 = 0.f, a2 = 0.f, a3 = 0.f;
    for (int i = 0; i < cnt; i += 4) {
        int s[4]; float ae[4], mk[4]; uint2 hp[4];
#pragma unroll
        for (int j = 0; j < 4; j++) {
            const int e = i + j;
            const int ec = (e < cnt) ? e : (cnt - 1);
            mk[j] = (e < cnt) ? 1.f : 0.f;
            s[j] = csr[rs + ec];
        }
#pragma unroll
        for (int j = 0; j < 4; j++) ae[j] = a_src[s[j] * 8 + head];
#pragma unroll
        for (int j = 0; j < 4; j++) hp[j] = h2[(size_t)s[j] * 32 + l];
#pragma unroll
        for (int j = 0; j < 4; j++) {
            float e = ae[j] + adn;
            e = (e > 0.f) ? e : 0.2f * e;      // leaky_relu(0.2)
            const float wgt = __expf(e) * mk[j];
            d_acc += wgt;
            a0 += wgt * bf2f(hp[j].x & 0xffffu);
            a1 += wgt * bf2f(hp[j].x >> 16);
            a2 += wgt * bf2f(hp[j].y & 0xffffu);
            a3 += wgt * bf2f(hp[j].y >> 16);
        }
    }
    const float inv = 1.0f / d_acc;
    const uint2 zp = z0b[(size_t)n * 32 + l];
    float y0 = a0 * inv + bf2f(zp.x & 0xffffu);
    float y1 = a1 * inv + bf2f(zp.x >> 16);
    float y2 = a2 * inv + bf2f(zp.y & 0xffffu);
    float y3 = a3 * inv + bf2f(zp.y >> 16);

    // LayerNorm over 128 cols (32-lane half-wave reduce)
    float ss = y0 + y1 + y2 + y3;
#pragma unroll
    for (int off = 1; off < 32; off <<= 1) ss += __shfl_xor(ss, off);
    const float mu = ss * (1.0f / 128.0f);
    const float d0 = y0 - mu, d1 = y1 - mu, d2 = y2 - mu, d3 = y3 - mu;
    float vs = d0 * d0 + d1 * d1 + d2 * d2 + d3 * d3;
#pragma unroll
    for (int off = 1; off < 32; off <<= 1) vs += __shfl_xor(vs, off);
    const float rstd = rsqrtf(vs * (1.0f / 128.0f) + 1e-5f);

    const float4 gv = *(const float4*)(gamma + l * 4);
    const float4 bv = *(const float4*)(beta + l * 4);
    float o0 = d0 * rstd * gv.x + bv.x;
    float o1 = d1 * rstd * gv.y + bv.y;
    float o2 = d2 * rstd * gv.z + bv.z;
    float o3 = d3 * rstd * gv.w + bv.w;
    o0 = (o0 > 0.f) ? o0 : (__expf(o0) - 1.0f);   // ELU
    o1 = (o1 > 0.f) ? o1 : (__expf(o1) - 1.0f);
    o2 = (o2 > 0.f) ? o2 : (__expf(o2) - 1.0f);
    o3 = (o3 > 0.f) ? o3 : (__expf(o3) - 1.0f);

    *(float4*)(out + (size_t)n * HC + l * 4) = make_float4(o0, o1, o2, o3);
}

// ---------------------------------------------------------------------------
extern "C" void kernel_launch(void* const* d_in, const int* in_sizes, int n_in,
                              void* d_out, int out_size, void* d_ws, size_t ws_size,
                              hipStream_t stream) {
    const float* x   = (const float*)d_in[0];
    const int*   ei  = (const int*)d_in[1];
    const float* Wg  = (const float*)d_in[2];
    const float* as_ = (const float*)d_in[3];
    const float* ad_ = (const float*)d_in[4];
    const float* bg  = (const float*)d_in[5];
    const float* Wsk = (const float*)d_in[6];
    const float* gm  = (const float*)d_in[7];
    const float* bt  = (const float*)d_in[8];
    float* out = (float*)d_out;

    // workspace layout (bytes), ~35.9 MB total
    char* wsb = (char*)d_ws;
    unsigned short* h_bf  = (unsigned short*)wsb;              // [N][128] bf16
    unsigned int*   z0b   = (unsigned int*)(wsb + 12800000);   // [N][64] bf16x2
    float*          a_src = (float*)(wsb + 25600000);          // [N][8]
    float*          a_dst = (float*)(wsb + 27200000);          // [N][8]
    unsigned short* Bfrag = (unsigned short*)(wsb + 28800000); // 64 KB
    int*   counts = (int*)(wsb + 28865536);                    // 50048
    int*   row_st = (int*)(wsb + 29065728);                    // 50048
    int*   bsum   = (int*)(wsb + 29265920);                    // 256
    int*   csr    = (int*)(wsb + 29266944);                    // 850000
    int*   part   = (int*)(wsb + 32666944);                    // 800000

    const int* src = ei;
    const int* dst = ei + N_EDGES;

    k_hist <<<144, 256, 0, stream>>>(dst, Wg, Wsk, Bfrag, part);
    k_merge<<<196, 256, 0, stream>>>(part, counts);
    k_scanA<<<49, 256, 0, stream>>>(counts, row_st, bsum);
    k_scanB<<<1, 64, 0, stream>>>(bsum, 49);
    k_scanC<<<196, 256, 0, stream>>>(row_st, bsum, counts, csr);
    k_lf   <<<910, 256, 0, stream>>>(x, Bfrag, as_, ad_, bg, h_bf, z0b,
                                     a_src, a_dst, src, dst, row_st, part, csr);
    k_agg  <<<N_NODES / 8, 256, 0, stream>>>((const uint2*)h_bf, (const uint2*)z0b,
                                             a_src, a_dst, row_st, counts, csr,
                                             gm, bt, out);
}